// Round 3
// baseline (451.229 us; speedup 1.0000x reference)
//
#include <hip/hip_runtime.h>
#include <math.h>

// CRF log-likelihood, B=512, S=512, T=128.
// ROUND 12: R11 + forced VGPR allocation. R11 post-mortem: VGPR_Count=92
// proved E (128 floats/lane) was allocated to AGPRs (waves_per_eu=1 splits
// the 512 unified budget arch/acc); every E use cost a v_accvgpr_read into
// a scarce temp pool, serializing the FMA block (measured VALU issue
// ~495 cyc/step vs ~240 expected). Fix: __launch_bounds__(128, 2) -> 256
// unified budget, no AGPR pool to fall back to; total need ~210 regs fits.
// Everything else identical to R11 (passed, absmax 0.0): 2 waves/batch,
// lgkm-only barrier (emission prefetch stays in flight), xor-swizzled
// 2x512B LDS p double-buffer (bank-conflict 0), DPP xor1/xor2 +
// ds_swizzle xor4 value-routed reduce, linear-domain recursion with exact
// accounting (Ld += log sref in double).

#define T 128
#define SLEN 512
#define BATCH 512

typedef float v2f __attribute__((ext_vector_type(2)));

static __device__ __forceinline__ float dpp_xor1(float x) {
    // quad_perm [1,0,3,2] == lane ^ 1
    return __int_as_float(__builtin_amdgcn_update_dpp(
        0, __float_as_int(x), 0xB1, 0xF, 0xF, true));
}
static __device__ __forceinline__ float dpp_xor2(float x) {
    // quad_perm [2,3,0,1] == lane ^ 2
    return __int_as_float(__builtin_amdgcn_update_dpp(
        0, __float_as_int(x), 0x4E, 0xF, 0xF, true));
}
static __device__ __forceinline__ float swz_xor4(float x) {
    // BitMode: and=0x1F, or=0, xor=4
    return __int_as_float(__builtin_amdgcn_ds_swizzle(__float_as_int(x), 0x101F));
}
static __device__ __forceinline__ void lgkm_barrier() {
    // LDS-writes-drained barrier that leaves vmcnt (global prefetch) alone.
    asm volatile("s_waitcnt lgkmcnt(0)\n\ts_barrier" ::: "memory");
}
// Bank swizzle for the 128-word p buffer: 4-word groups xor'd by (j>>5).
static __device__ __forceinline__ int pslot(int j) {
    return j ^ (((j >> 5) & 3) << 2);
}

__global__ __launch_bounds__(128, 2) void fwd_kernel(
    const float* __restrict__ em, const int* __restrict__ tags,
    const int* __restrict__ mask, const float* __restrict__ startT,
    const float* __restrict__ endT, const float* __restrict__ trans,
    float* __restrict__ ws)
{
    const int tid  = threadIdx.x;      // 0..127
    const int lane = tid & 63;
    const int w    = tid >> 6;         // wave 0/1: output cols 64w..64w+63
    const int rg   = lane & 7;         // row group: rows 16rg..16rg+15
    const int cg   = lane >> 3;        // col group: cols 64w+8cg..+7
    const int b    = blockIdx.x;
    const int rb0  = rg & 1, rb1 = (rg >> 1) & 1, rb2 = (rg >> 2) & 1;
    // After the 3 routed butterfly stages this lane owns exactly this col:
    const int mycol = 64 * w + 8 * cg + 4 * rb0 + 2 * rb1 + rb2;

    const float* emb = em + (size_t)b * SLEN * T;
    const int*   mk  = mask + (size_t)b * SLEN;

    __shared__ __align__(16) float p_lds[2][T];   // double buffer, 1 KB
    __shared__ float reds[2], redn[2];
    __shared__ int   redc[2];

    // Rotated row-chunk schedule + swizzled read slots.
    int rbase[4], rslot[4];
#pragma unroll
    for (int k = 0; k < 4; ++k) {
        rbase[k] = 16 * rg + 4 * ((k + rg) & 3);
        rslot[k] = pslot(rbase[k]);    // 4-word group shares one xor
    }
    const int wslot = pslot(mycol);

    // E fragment: Elo[k][c] = (exp(trans[r0][col]), exp(trans[r0+1][col])),
    // Ehi = rows (r0+2, r0+3); r0 = rbase[k], col = 64w + 8cg + c.
    // 64 v2f = 128 VGPRs.
    v2f Elo[4][8], Ehi[4][8];
    {
        const int cb = 64 * w + 8 * cg;
#pragma unroll
        for (int k = 0; k < 4; ++k) {
            const float* t0p = trans + (rbase[k] + 0) * T + cb;
            const float* t1p = t0p + T;
            const float* t2p = t1p + T;
            const float* t3p = t2p + T;
#pragma unroll
            for (int c = 0; c < 8; ++c) {
                Elo[k][c] = (v2f){ __expf(t0p[c]), __expf(t1p[c]) };
                Ehi[k][c] = (v2f){ __expf(t2p[c]), __expf(t3p[c]) };
            }
        }
    }

    // alpha_0 in linear domain; step 1 reads buffer 1.
    float pprev = __expf(startT[mycol] + emb[mycol]);
    p_lds[1][wslot] = pprev;
    double Ld = 0.0;

    // 4-deep emission/mask prefetch; exp applied off-chain.
    float emv[4], emn[4];
    int   mkv[4], mkn[4];
#pragma unroll
    for (int k = 0; k < 4; ++k) {
        emv[k] = __expf(emb[(1 + k) * T + mycol]);
        mkv[k] = mk[1 + k];
    }
    lgkm_barrier();

    for (int s0 = 1; s0 < SLEN; s0 += 4) {
#pragma unroll
        for (int k = 0; k < 4; ++k) {
            int ss = s0 + 4 + k; ss = (ss < SLEN) ? ss : (SLEN - 1);  // uniform
            emn[k] = emb[ss * T + mycol];
            mkn[k] = mk[ss];
        }
#pragma unroll
        for (int k = 0; k < 4; ++k) {
            const int s = s0 + k;
            if (s < SLEN) {                       // uniform guard (511 steps)
                const int cur = (1 + k) & 1;      // == s&1, compile-time
                // Off-chain normalizer: col 0 (slot 0) of input buffer.
                const float sref0 = p_lds[cur][0];
                const float srefc = fmaxf(sref0, 1e-30f);
                const float cc = __builtin_amdgcn_rcpf(srefc);
                Ld += (double)__logf(srefc);      // exact accounting

                // p chunks (swizzled slots: conflict-free b128 reads).
                v2f pk0[4], pk1[4];
#pragma unroll
                for (int kk = 0; kk < 4; ++kk) {
                    const float4 pv = *(const float4*)&p_lds[cur][rslot[kk]];
                    pk0[kk] = (v2f){ pv.x, pv.y };
                    pk1[kk] = (v2f){ pv.z, pv.w };
                }
                // 64 pk_fma: 8 cols x 8-deep row-pair chains.
                v2f acc[8];
#pragma unroll
                for (int c = 0; c < 8; ++c)
                    acc[c] = pk0[0] * Elo[0][c];
#pragma unroll
                for (int c = 0; c < 8; ++c)
                    acc[c] = __builtin_elementwise_fma(pk1[0], Ehi[0][c], acc[c]);
#pragma unroll
                for (int kk = 1; kk < 4; ++kk) {
#pragma unroll
                    for (int c = 0; c < 8; ++c) {
                        acc[c] = __builtin_elementwise_fma(pk0[kk], Elo[kk][c], acc[c]);
                        acc[c] = __builtin_elementwise_fma(pk1[kk], Ehi[kk][c], acc[c]);
                    }
                }
                float sv[8];
#pragma unroll
                for (int c = 0; c < 8; ++c) sv[c] = acc[c].x + acc[c].y;

                // Value-routed reduce over 8 rg lanes (3 stages).
                float v1[4];
#pragma unroll
                for (int c = 0; c < 4; ++c)
                    v1[c] = (rb0 ? sv[c + 4] : sv[c])
                          + dpp_xor1(rb0 ? sv[c] : sv[c + 4]);
                float v2_[2];
#pragma unroll
                for (int c = 0; c < 2; ++c)
                    v2_[c] = (rb1 ? v1[c + 2] : v1[c])
                           + dpp_xor2(rb1 ? v1[c] : v1[c + 2]);
                const float t = (rb2 ? v2_[1] : v2_[0])
                              + swz_xor4(rb2 ? v2_[0] : v2_[1]);

                // Linear-domain update; mask=0 keeps alpha (scaled by cc).
                const float pn = t * (emv[k] * cc);
                const float pm = pprev * cc;
                pprev = (mkv[k] > 0) ? pn : pm;
                p_lds[cur ^ 1][wslot] = pprev;
                lgkm_barrier();                   // no vmcnt drain
            }
        }
#pragma unroll
        for (int k = 0; k < 4; ++k) { emv[k] = __expf(emn[k]); mkv[k] = mkn[k]; }
    }

    // ---- denominator: log(sum_j p_j e^endT_j) + Ld ----
    const float eendv = __expf(endT[mycol]);      // loaded after loop: no
    float sm = pprev * eendv;                     // loop-carried register
#pragma unroll
    for (int off = 32; off; off >>= 1) sm += __shfl_xor(sm, off);
    if (lane == 0) reds[w] = sm;

    // ---- numerator: 4 strided steps per thread ----
    const int* tg = tags + (size_t)b * SLEN;
    float nv = 0.f; int cnt = 0;
#pragma unroll
    for (int rep = 0; rep < 4; ++rep) {
        const int s = tid + 128 * rep;
        const int mm = mk[s];
        cnt += (mm != 0);
        if (s >= 1 && mm > 0)
            nv += trans[tg[s - 1] * T + tg[s]] + emb[s * T + tg[s]];
    }
#pragma unroll
    for (int off = 32; off; off >>= 1) {
        nv  += __shfl_xor(nv, off);
        cnt += __shfl_xor(cnt, off);
    }
    if (lane == 0) { redn[w] = nv; redc[w] = cnt; }
    __syncthreads();
    if (tid == 0) {
        const float ssum = reds[0] + reds[1];
        const float nsum = redn[0] + redn[1];
        const int seqlen = redc[0] + redc[1];
        const float denom = __logf(ssum) + (float)Ld;
        const int t0g = tg[0], tl = tg[seqlen - 1];
        ws[b] = (startT[t0g] + emb[t0g] + endT[tl] + nsum) - denom;
    }
}

__global__ __launch_bounds__(256) void reduce_kernel(
    const float* __restrict__ ws, float* __restrict__ out)
{
    const int t = threadIdx.x;          // one block of 256
    float local = 0.f;
    for (int i = t; i < BATCH; i += 256) local += ws[i];
    __shared__ float rf[256];
    rf[t] = local;
    __syncthreads();
    for (int off = 128; off > 0; off >>= 1) {
        if (t < off) rf[t] += rf[t + off];
        __syncthreads();
    }
    if (t == 0) out[0] = rf[0];
}

extern "C" void kernel_launch(void* const* d_in, const int* in_sizes, int n_in,
                              void* d_out, int out_size, void* d_ws, size_t ws_size,
                              hipStream_t stream)
{
    const float* emissions = (const float*)d_in[0];
    const int*   tags      = (const int*)d_in[1];
    const int*   mask      = (const int*)d_in[2];
    const float* startT    = (const float*)d_in[3];
    const float* endT      = (const float*)d_in[4];
    const float* trans     = (const float*)d_in[5];
    float* out = (float*)d_out;
    float* ws  = (float*)d_ws;          // BATCH floats of per-batch partials

    fwd_kernel<<<BATCH, 128, 0, stream>>>(emissions, tags, mask, startT, endT, trans, ws);
    reduce_kernel<<<1, 256, 0, stream>>>(ws, out);
}

// Round 4
// 369.253 us; speedup vs baseline: 1.2220x; 1.2220x over previous
//
#include <hip/hip_runtime.h>
#include <math.h>

// CRF log-likelihood, B=512, S=512, T=128.
// ROUND 13: back to 4 waves/batch (2 waves/SIMD) + all R11/R12 wins.
// R12 post-mortem: 2-wave layout leaves 1 wave/SIMD (Occupancy 9.9%) ->
// every ds_read/barrier stall fully exposed, and the lone wave issues
// ~246 insts/step (incl ~128 v_accvgpr_read: compiler keeps E in AGPRs
// regardless of launch_bounds; VGPR_Count 92/96 proves it) -> 1541 cyc/step.
// Fix: 256 thr/batch (4 waves), E = 16 rows x 4 cols = 64 floats/lane.
// 2048 waves total = 2 waves/SIMD from INDEPENDENT blocks: one batch's
// barrier/LDS stalls are filled by the other batch's FMA issue.
// Kept from R11/R12 (both passed, absmax 0.0):
//  - lgkm-only barrier (s_waitcnt lgkmcnt(0); s_barrier) - emission
//    prefetch stays in flight across sync (no vmcnt drain).
//  - DPP quad_perm xor1/xor2 + ds_swizzle xor4 value-routed reduce.
//  - xor-swizzled p double buffer (identical per-wave pattern measured
//    SQ_LDS_BANK_CONFLICT = 0 in R12).
//  - linear-domain recursion + exact accounting (Ld += log sref, double).
// Reduce leaves each col duplicated on lane pairs (rb2); duplicate writes
// are same-address same-value (benign); final sum halved by exact 0.5f.

#define T 128
#define SLEN 512
#define BATCH 512

typedef float v2f __attribute__((ext_vector_type(2)));

static __device__ __forceinline__ float dpp_xor1(float x) {
    // quad_perm [1,0,3,2] == lane ^ 1
    return __int_as_float(__builtin_amdgcn_update_dpp(
        0, __float_as_int(x), 0xB1, 0xF, 0xF, true));
}
static __device__ __forceinline__ float dpp_xor2(float x) {
    // quad_perm [2,3,0,1] == lane ^ 2
    return __int_as_float(__builtin_amdgcn_update_dpp(
        0, __float_as_int(x), 0x4E, 0xF, 0xF, true));
}
static __device__ __forceinline__ float swz_xor4(float x) {
    // BitMode: and=0x1F, or=0, xor=4
    return __int_as_float(__builtin_amdgcn_ds_swizzle(__float_as_int(x), 0x101F));
}
static __device__ __forceinline__ void lgkm_barrier() {
    // LDS-writes-drained barrier that leaves vmcnt (global prefetch) alone.
    asm volatile("s_waitcnt lgkmcnt(0)\n\ts_barrier" ::: "memory");
}
// Bank swizzle for the 128-word p buffer: 4-word groups xor'd by (j>>5).
static __device__ __forceinline__ int pslot(int j) {
    return j ^ (((j >> 5) & 3) << 2);
}

__global__ __launch_bounds__(256, 2) void fwd_kernel(
    const float* __restrict__ em, const int* __restrict__ tags,
    const int* __restrict__ mask, const float* __restrict__ startT,
    const float* __restrict__ endT, const float* __restrict__ trans,
    float* __restrict__ ws)
{
    const int tid  = threadIdx.x;      // 0..255
    const int lane = tid & 63;
    const int w    = tid >> 6;         // wave 0..3
    const int rg   = lane & 7;         // row group: rows 16rg..16rg+15
    const int cw   = lane >> 3;        // col subgroup within wave (0..7)
    const int g    = 8 * w + cw;       // col group 0..31: cols 4g..4g+3
    const int b    = blockIdx.x;
    const int rb0  = rg & 1, rb1 = (rg >> 1) & 1, rb2 = (rg >> 2) & 1;
    // After the 3 routed butterfly stages this lane owns exactly this col
    // (duplicated across the rb2 pair):
    const int mycol = 4 * g + 2 * rb0 + rb1;

    const float* emb = em + (size_t)b * SLEN * T;
    const int*   mk  = mask + (size_t)b * SLEN;

    __shared__ __align__(16) float p_lds[2][T];   // double buffer, 1 KB
    __shared__ float reds[4], redn[4];
    __shared__ int   redc[4];

    // Rotated row-chunk schedule + swizzled read slots (R12-verified: 0 conflicts).
    int rbase[4], rslot[4];
#pragma unroll
    for (int k = 0; k < 4; ++k) {
        rbase[k] = 16 * rg + 4 * ((k + rg) & 3);
        rslot[k] = pslot(rbase[k]);    // 4-word group shares one xor
    }
    const int wslot = pslot(mycol);

    // E fragment: Elo[k][c] = (exp(trans[r0][col]), exp(trans[r0+1][col])),
    // Ehi = rows (r0+2, r0+3); r0 = rbase[k], col = 4g + c.  32 v2f = 64 regs.
    v2f Elo[4][4], Ehi[4][4];
    {
        const int cb = 4 * g;
#pragma unroll
        for (int k = 0; k < 4; ++k) {
            const float* t0p = trans + (rbase[k] + 0) * T + cb;
            const float* t1p = t0p + T;
            const float* t2p = t1p + T;
            const float* t3p = t2p + T;
#pragma unroll
            for (int c = 0; c < 4; ++c) {
                Elo[k][c] = (v2f){ __expf(t0p[c]), __expf(t1p[c]) };
                Ehi[k][c] = (v2f){ __expf(t2p[c]), __expf(t3p[c]) };
            }
        }
    }

    // alpha_0 in linear domain; step 1 reads buffer 1. Duplicate writers
    // store bit-identical values to the same slot: benign.
    float pprev = __expf(startT[mycol] + emb[mycol]);
    p_lds[1][wslot] = pprev;
    double Ld = 0.0;

    // 4-deep emission/mask prefetch; exp applied off-chain.
    float emv[4], emn[4];
    int   mkv[4], mkn[4];
#pragma unroll
    for (int k = 0; k < 4; ++k) {
        emv[k] = __expf(emb[(1 + k) * T + mycol]);
        mkv[k] = mk[1 + k];
    }
    lgkm_barrier();

    for (int s0 = 1; s0 < SLEN; s0 += 4) {
#pragma unroll
        for (int k = 0; k < 4; ++k) {
            int ss = s0 + 4 + k; ss = (ss < SLEN) ? ss : (SLEN - 1);  // uniform
            emn[k] = emb[ss * T + mycol];
            mkn[k] = mk[ss];
        }
#pragma unroll
        for (int k = 0; k < 4; ++k) {
            const int s = s0 + k;
            if (s < SLEN) {                       // uniform guard (511 steps)
                const int cur = (1 + k) & 1;      // == s&1, compile-time
                // Off-chain normalizer: col 0 (slot 0) of input buffer.
                const float sref0 = p_lds[cur][0];
                const float srefc = fmaxf(sref0, 1e-30f);
                const float cc = __builtin_amdgcn_rcpf(srefc);
                Ld += (double)__logf(srefc);      // exact accounting

                // p chunks (swizzled slots: conflict-free b128 reads).
                v2f pk0[4], pk1[4];
#pragma unroll
                for (int kk = 0; kk < 4; ++kk) {
                    const float4 pv = *(const float4*)&p_lds[cur][rslot[kk]];
                    pk0[kk] = (v2f){ pv.x, pv.y };
                    pk1[kk] = (v2f){ pv.z, pv.w };
                }
                // 32 pk_fma: 4 cols x 8-deep row-pair chains.
                v2f acc[4];
#pragma unroll
                for (int c = 0; c < 4; ++c)
                    acc[c] = pk0[0] * Elo[0][c];
#pragma unroll
                for (int c = 0; c < 4; ++c)
                    acc[c] = __builtin_elementwise_fma(pk1[0], Ehi[0][c], acc[c]);
#pragma unroll
                for (int kk = 1; kk < 4; ++kk) {
#pragma unroll
                    for (int c = 0; c < 4; ++c) {
                        acc[c] = __builtin_elementwise_fma(pk0[kk], Elo[kk][c], acc[c]);
                        acc[c] = __builtin_elementwise_fma(pk1[kk], Ehi[kk][c], acc[c]);
                    }
                }
                float sv[4];
#pragma unroll
                for (int c = 0; c < 4; ++c) sv[c] = acc[c].x + acc[c].y;

                // Value-routed reduce over 8 rg lanes (3 stages).
                float v1[2];
#pragma unroll
                for (int c = 0; c < 2; ++c)
                    v1[c] = (rb0 ? sv[c + 2] : sv[c])
                          + dpp_xor1(rb0 ? sv[c] : sv[c + 2]);
                const float v2_ = (rb1 ? v1[1] : v1[0])
                                + dpp_xor2(rb1 ? v1[0] : v1[1]);
                const float t = v2_ + swz_xor4(v2_);   // dup across rb2 pair

                // Linear-domain update; mask=0 keeps alpha (scaled by cc).
                const float pn = t * (emv[k] * cc);
                const float pm = pprev * cc;
                pprev = (mkv[k] > 0) ? pn : pm;
                p_lds[cur ^ 1][wslot] = pprev;    // dup same-value writes
                lgkm_barrier();                   // no vmcnt drain
            }
        }
#pragma unroll
        for (int k = 0; k < 4; ++k) { emv[k] = __expf(emn[k]); mkv[k] = mkn[k]; }
    }

    // ---- denominator: log(sum_j p_j e^endT_j) + Ld ----
    // Each col is duplicated on an rb2 lane pair -> wave sums are exactly 2x;
    // halve with an exact 0.5f at the end.
    const float eendv = __expf(endT[mycol]);
    float sm = pprev * eendv;
#pragma unroll
    for (int off = 32; off; off >>= 1) sm += __shfl_xor(sm, off);
    if (lane == 0) reds[w] = sm;

    // ---- numerator: 2 strided steps per thread ----
    const int* tg = tags + (size_t)b * SLEN;
    float nv = 0.f; int cnt = 0;
#pragma unroll
    for (int rep = 0; rep < 2; ++rep) {
        const int s = tid + 256 * rep;
        const int mm = mk[s];
        cnt += (mm != 0);
        if (s >= 1 && mm > 0)
            nv += trans[tg[s - 1] * T + tg[s]] + emb[s * T + tg[s]];
    }
#pragma unroll
    for (int off = 32; off; off >>= 1) {
        nv  += __shfl_xor(nv, off);
        cnt += __shfl_xor(cnt, off);
    }
    if (lane == 0) { redn[w] = nv; redc[w] = cnt; }
    __syncthreads();
    if (tid == 0) {
        float ssum = 0.f, nsum = 0.f; int seqlen = 0;
#pragma unroll
        for (int i = 0; i < 4; ++i) {
            ssum += reds[i]; nsum += redn[i]; seqlen += redc[i];
        }
        const float denom = __logf(0.5f * ssum) + (float)Ld;  // exact halving
        const int t0g = tg[0], tl = tg[seqlen - 1];
        ws[b] = (startT[t0g] + emb[t0g] + endT[tl] + nsum) - denom;
    }
}

__global__ __launch_bounds__(256) void reduce_kernel(
    const float* __restrict__ ws, float* __restrict__ out)
{
    const int t = threadIdx.x;          // one block of 256
    float local = 0.f;
    for (int i = t; i < BATCH; i += 256) local += ws[i];
    __shared__ float rf[256];
    rf[t] = local;
    __syncthreads();
    for (int off = 128; off > 0; off >>= 1) {
        if (t < off) rf[t] += rf[t + off];
        __syncthreads();
    }
    if (t == 0) out[0] = rf[0];
}

extern "C" void kernel_launch(void* const* d_in, const int* in_sizes, int n_in,
                              void* d_out, int out_size, void* d_ws, size_t ws_size,
                              hipStream_t stream)
{
    const float* emissions = (const float*)d_in[0];
    const int*   tags      = (const int*)d_in[1];
    const int*   mask      = (const int*)d_in[2];
    const float* startT    = (const float*)d_in[3];
    const float* endT      = (const float*)d_in[4];
    const float* trans     = (const float*)d_in[5];
    float* out = (float*)d_out;
    float* ws  = (float*)d_ws;          // BATCH floats of per-batch partials

    fwd_kernel<<<BATCH, 256, 0, stream>>>(emissions, tags, mask, startT, endT, trans, ws);
    reduce_kernel<<<1, 256, 0, stream>>>(ws, out);
}